// Round 12
// baseline (154.258 us; speedup 1.0000x reference)
//
#include <hip/hip_runtime.h>
#include <hip/hip_bf16.h>

#define DIM    286
#define DIMP   288
#define NZTOT  55296     // 48*24*48
#define NBATCH 256
#define NB_    24
#define NA_    48
#define ZC     32        // z per tile
#define NTILES 1728      // NZTOT/ZC
#define NCHUNK 288       // z-chunk workgroups (grid.x): 576 blocks = 2.25/CU
#define TILES_PER_WG 6   // NTILES/NCHUNK
#define S_CONST 16.911534525287763f
#define INV_S   0.05913123959890826f
#define ACT_CST 1.5927f  // normalize2mom const for tanh

typedef short bf16x8 __attribute__((ext_vector_type(8)));
typedef float f32x4  __attribute__((ext_vector_type(4)));

// ws layout (bytes)
#define WS_FBF  0u
#define WS_DBF  147456u                      // Fbf: 256*288*2
#define WS_DT   (WS_DBF + 31850496u)         // Dbf: 55296*288*2
#define WS_PART (WS_DT + 31850496u)          // Dt2: 1728 tiles * 288 * 32 * 2
                                             // part (bf16): 288*256*288*2 = 42467328

typedef const __attribute__((address_space(1))) char GA;
typedef __attribute__((address_space(3))) char LA;
__device__ __forceinline__ void gload_lds16(const void* g, void* l) {
    __builtin_amdgcn_global_load_lds((GA*)g, (LA*)l, 16, 0, 0);
}

// ---------- fused prep: blocks [0,1728) do D->Dbf/Dt2 via DMA-flat LDS; [1728,2016) F->Fbf
__global__ void k_prep(const float* __restrict__ F, const float* __restrict__ D,
                       const float* __restrict__ qw,
                       __hip_bfloat16* __restrict__ Fbf,
                       __hip_bfloat16* __restrict__ Dbf, __hip_bfloat16* __restrict__ Dt2) {
    __shared__ __align__(16) float T[9152];   // flat 32*286 fp32 = 36608 B
    __shared__ float qs[24];
    int t = threadIdx.x;
    int bid = blockIdx.x;
    if (bid >= NTILES) {
        // ---- prep_f: F -> bf16 [256][288], scaled by 1/s
        int o = (bid - NTILES) * 256 + t;    // 288*256 == 73728 exactly
        int row = o / DIMP, col = o % DIMP;
        float v = (col < DIM) ? F[row * DIM + col] * INV_S : 0.f;
        Fbf[o] = __float2bfloat16(v);
        return;
    }
    int z0 = bid * 32;
    if (t < 24) qs[t] = qw[t] * S_CONST;
    // DMA: 36608 B = 35 full 1KB chunks + 768 B tail (48 lanes)
    {
        int wave = t >> 6, lane = t & 63;
        const char* src = (const char*)(D + (size_t)z0 * DIM);
        char* dst = (char*)T;
        #pragma unroll
        for (int j = 0; j < 9; ++j) {
            int c = wave + j * 4;
            if (c < 35 || (c == 35 && lane < 48))
                gload_lds16(src + c * 1024 + lane * 16, dst + c * 1024);
        }
    }
    asm volatile("s_waitcnt vmcnt(0)" ::: "memory");
    __syncthreads();
    // Dbf: lane-consecutive float2 -> bf162, 4608 dwords (18 iters), conflict-free b64 reads
    for (int m = 0; m < 18; ++m) {
        int d = t + m * 256;                 // 0..4607
        int z = d / 144, i2 = d % 144;
        int i = i2 * 2;
        __hip_bfloat162 o2;
        if (i < DIM) {
            float2 v = *(const float2*)(&T[z * DIM + i]);   // z*286+i even -> 8B aligned
            o2.x = __float2bfloat16(v.x); o2.y = __float2bfloat16(v.y);
        } else {
            o2.x = __float2bfloat16(0.f); o2.y = o2.x;      // pad cols 286..287
        }
        *(__hip_bfloat162*)(Dbf + (size_t)(z0 + z) * DIMP + i) = o2;
    }
    // Dt2[tz][i][z] transpose: 288 i * 4 zc = 1152 contiguous 16B writes
    for (int s = 0; s < 5; ++s) {
        int idx = t + s * 256;
        if (idx < 1152) {
            int i = idx >> 2, zc = idx & 3;
            __hip_bfloat16 o8[8];
            #pragma unroll
            for (int j = 0; j < 8; ++j) {
                int zl = zc * 8 + j;
                int y = ((z0 + zl) / NA_) % NB_;
                o8[j] = __float2bfloat16(T[zl * DIM + i] * qs[y]);
            }
            *(bf16x8*)(Dt2 + ((size_t)bid * DIMP + i) * ZC + zc * 8) = *(const bf16x8*)o8;
        }
    }
}

// ---------- fused main, M=32 per wave (R10 structure: sequential stage + single drain)
__launch_bounds__(256, 2)
__global__ void k_main(const __hip_bfloat16* __restrict__ Fbf,
                       const __hip_bfloat16* __restrict__ Dbf,
                       const __hip_bfloat16* __restrict__ Dt2,
                       __hip_bfloat16* __restrict__ part) {
    __shared__ __align__(16) __hip_bfloat16 Ds[32][288];    // [z][i]  18432 B
    __shared__ __align__(16) __hip_bfloat16 Dts[288][32];   // [i][z]  18432 B
    __shared__ __align__(16) __hip_bfloat16 Gs[4][32][32];  // 8192 B -> total 45056 B

    int t = threadIdx.x;
    int wave = t >> 6, lane = t & 63, ln = lane & 15, q = lane >> 4;

    // cache F A-frags for this wave's 32 batch rows (2 halves x 9 K-steps)
    bf16x8 fa[2][9];
    int rowbase = blockIdx.y * 128 + wave * 32;
    #pragma unroll
    for (int h = 0; h < 2; ++h) {
        const __hip_bfloat16* fp = Fbf + (size_t)(rowbase + h * 16 + ln) * DIMP + q * 8;
        #pragma unroll
        for (int ks = 0; ks < 9; ++ks) fa[h][ks] = *(const bf16x8*)(fp + ks * 32);
    }

    f32x4 acc[2][18];
    #pragma unroll
    for (int h = 0; h < 2; ++h)
        #pragma unroll
        for (int n = 0; n < 18; ++n) acc[h][n] = (f32x4){0.f, 0.f, 0.f, 0.f};

    #pragma unroll 1
    for (int k = 0; k < TILES_PER_WG; ++k) {
        int tz = blockIdx.x + k * NCHUNK;
        // stage: waves 0,1 -> Ds halves; waves 2,3 -> Dts halves; 9x1KB DMA each
        {
            const char* src; char* dst;
            if (wave < 2) {
                src = (const char*)(Dbf + (size_t)tz * ZC * DIMP) + wave * 9216 + lane * 16;
                dst = ((char*)&Ds[0][0]) + wave * 9216;
            } else {
                src = (const char*)(Dt2 + (size_t)tz * DIMP * ZC) + (wave - 2) * 9216 + lane * 16;
                dst = ((char*)&Dts[0][0]) + (wave - 2) * 9216;
            }
            #pragma unroll
            for (int j = 0; j < 9; ++j)
                gload_lds16(src + j * 1024, dst + j * 1024);
        }
        asm volatile("s_waitcnt vmcnt(0)" ::: "memory");   // DMA landed
        __syncthreads();
        // GEMM1: G[32 x 32] per wave, K=288; B-frags read once for 2 row-halves
        f32x4 g00 = (f32x4){0.f,0.f,0.f,0.f}, g01 = (f32x4){0.f,0.f,0.f,0.f};
        f32x4 g10 = (f32x4){0.f,0.f,0.f,0.f}, g11 = (f32x4){0.f,0.f,0.f,0.f};
        #pragma unroll
        for (int ks = 0; ks < 9; ++ks) {
            bf16x8 b0 = *(const bf16x8*)(&Ds[ln][ks * 32 + q * 8]);
            bf16x8 b1 = *(const bf16x8*)(&Ds[16 + ln][ks * 32 + q * 8]);
            g00 = __builtin_amdgcn_mfma_f32_16x16x32_bf16(fa[0][ks], b0, g00, 0, 0, 0);
            g01 = __builtin_amdgcn_mfma_f32_16x16x32_bf16(fa[0][ks], b1, g01, 0, 0, 0);
            g10 = __builtin_amdgcn_mfma_f32_16x16x32_bf16(fa[1][ks], b0, g10, 0, 0, 0);
            g11 = __builtin_amdgcn_mfma_f32_16x16x32_bf16(fa[1][ks], b1, g11, 0, 0, 0);
        }
        // act + C-layout -> A-layout relayout (per-wave LDS, no barrier)
        #pragma unroll
        for (int h = 0; h < 2; ++h) {
            #pragma unroll
            for (int zh = 0; zh < 2; ++zh) {
                f32x4 g = (h == 0) ? (zh == 0 ? g00 : g01) : (zh == 0 ? g10 : g11);
                #pragma unroll
                for (int r = 0; r < 4; ++r) {
                    float x = g[r];
                    float a = fabsf(x);
                    float e = __expf(-2.f * a);
                    float th = (1.f - e) / (1.f + e);
                    float v = copysignf(ACT_CST * th, x);
                    Gs[wave][h * 16 + q * 4 + r][zh * 16 + ln] = __float2bfloat16(v);
                }
            }
        }
        // GEMM2: Out[32 x 288] += P[32 x 32] * Dts; B-frags read once for 2 row-halves
        bf16x8 a20 = *(const bf16x8*)(&Gs[wave][ln][q * 8]);
        bf16x8 a21 = *(const bf16x8*)(&Gs[wave][16 + ln][q * 8]);
        #pragma unroll
        for (int nf = 0; nf < 18; ++nf) {
            bf16x8 b2 = *(const bf16x8*)(&Dts[nf * 16 + ln][q * 8]);
            acc[0][nf] = __builtin_amdgcn_mfma_f32_16x16x32_bf16(a20, b2, acc[0][nf], 0, 0, 0);
            acc[1][nf] = __builtin_amdgcn_mfma_f32_16x16x32_bf16(a21, b2, acc[1][nf], 0, 0, 0);
        }
        __syncthreads();   // protect Ds/Dts before next stage
    }
    // epilogue: permuted coalesced layout, 18 b128 stores/thread.
    // elem ((h*9+m)*64 + lane)*8 + j  <=>  acc[h][2m + (j>>2)][j&3]
    __hip_bfloat16* pw = part + (size_t)blockIdx.x * (NBATCH * DIMP)
                       + ((size_t)blockIdx.y * 128 + wave * 32) * DIMP;
    #pragma unroll
    for (int h = 0; h < 2; ++h) {
        #pragma unroll
        for (int m = 0; m < 9; ++m) {
            __hip_bfloat16 o8[8];
            #pragma unroll
            for (int j = 0; j < 8; ++j)
                o8[j] = __float2bfloat16(acc[h][2 * m + (j >> 2)][j & 3]);
            *(bf16x8*)(pw + (size_t)((h * 9 + m) * 64 + lane) * 8) = *(const bf16x8*)o8;
        }
    }
}

// ---------- reduce permuted bf16 partials over 288 z-chunks: 576 blocks x 16 slots
__global__ void k_reduce(const __hip_bfloat16* __restrict__ part, float* __restrict__ out) {
    __shared__ float red[3][16][8];
    int t = threadIdx.x, wave = t >> 6, lane = t & 63;
    int j = lane & 15;                 // slot within block
    int zg = wave * 4 + (lane >> 4);   // 0..15 zc-group (18 chunks each)
    int s = blockIdx.x * 16 + j;       // 576*16 = 9216 b128 slots per chunk
    const __hip_bfloat16* p = part + (size_t)s * 8;
    float sum[8];
    #pragma unroll
    for (int kk = 0; kk < 8; ++kk) sum[kk] = 0.f;
    #pragma unroll 6
    for (int ii = 0; ii < 18; ++ii) {
        bf16x8 v = *(const bf16x8*)(p + (size_t)(zg * 18 + ii) * (NBATCH * DIMP));
        #pragma unroll
        for (int kk = 0; kk < 8; ++kk) {
            __hip_bfloat16 h; *(short*)&h = v[kk];
            sum[kk] += __bfloat162float(h);
        }
    }
    // intra-wave: fold the 4 zc-groups (lane strides 16, 32)
    #pragma unroll
    for (int kk = 0; kk < 8; ++kk) {
        sum[kk] += __shfl_down(sum[kk], 16);
        sum[kk] += __shfl_down(sum[kk], 32);
    }
    if (wave > 0 && lane < 16) {
        #pragma unroll
        for (int kk = 0; kk < 8; ++kk) red[wave - 1][lane][kk] = sum[kk];
    }
    __syncthreads();
    if (wave == 0 && lane < 16) {
        #pragma unroll
        for (int w = 0; w < 3; ++w)
            #pragma unroll
            for (int kk = 0; kk < 8; ++kk) sum[kk] += red[w][lane][kk];
        // decode slot s -> (rows, cols)
        int wr = s / 1152, si = s % 1152;
        int lane_m = si % 64, m9 = si / 64;
        int h = m9 / 9, m = m9 % 9, q = lane_m >> 4, ln = lane_m & 15;
        int rowb = wr * 32 + h * 16 + q * 4;
        #pragma unroll
        for (int j8 = 0; j8 < 8; ++j8) {
            int nf = 2 * m + (j8 >> 2), r = j8 & 3;
            int i = nf * 16 + ln;
            if (i < DIM) out[(rowb + r) * DIM + i] = sum[j8];
        }
    }
}

extern "C" void kernel_launch(void* const* d_in, const int* in_sizes, int n_in,
                              void* d_out, int out_size, void* d_ws, size_t ws_size,
                              hipStream_t stream) {
    const float* F  = (const float*)d_in[0];
    const float* D  = (const float*)d_in[1];
    const float* qw = (const float*)d_in[2];
    char* ws = (char*)d_ws;
    __hip_bfloat16* Fbf = (__hip_bfloat16*)(ws + WS_FBF);
    __hip_bfloat16* Dbf = (__hip_bfloat16*)(ws + WS_DBF);
    __hip_bfloat16* Dt2 = (__hip_bfloat16*)(ws + WS_DT);
    __hip_bfloat16* part = (__hip_bfloat16*)(ws + WS_PART);

    k_prep<<<NTILES + 288, 256, 0, stream>>>(F, D, qw, Fbf, Dbf, Dt2);
    k_main<<<dim3(NCHUNK, 2), 256, 0, stream>>>(Fbf, Dbf, Dt2, part);
    k_reduce<<<576, 256, 0, stream>>>(part, (float*)d_out);
}

// Round 13
// 141.976 us; speedup vs baseline: 1.0865x; 1.0865x over previous
//
#include <hip/hip_runtime.h>
#include <hip/hip_bf16.h>

#define DIM    286
#define DIMP   288
#define NZTOT  55296     // 48*24*48
#define NBATCH 256
#define NB_    24
#define NA_    48
#define ZC     32        // z per tile
#define NTILES 1728      // NZTOT/ZC
#define NCHUNK 192       // z-chunk workgroups (grid.x)
#define TILES_PER_WG 9   // NTILES/NCHUNK
#define S_CONST 16.911534525287763f
#define INV_S   0.05913123959890826f
#define ACT_CST 1.5927f  // normalize2mom const for tanh

typedef short bf16x8 __attribute__((ext_vector_type(8)));
typedef float f32x4  __attribute__((ext_vector_type(4)));

// ws layout (bytes)
#define WS_FBF  0u
#define WS_DBF  147456u                      // Fbf: 256*288*2
#define WS_DT   (WS_DBF + 31850496u)         // Dbf: 55296*288*2
#define WS_PART (WS_DT + 31850496u)          // Dt2: 1728 tiles * 288 * 32 * 2
                                             // part (bf16): 192*256*288*2 = 28311552

typedef const __attribute__((address_space(1))) char GA;
typedef __attribute__((address_space(3))) char LA;
__device__ __forceinline__ void gload_lds16(const void* g, void* l) {
    __builtin_amdgcn_global_load_lds((GA*)g, (LA*)l, 16, 0, 0);
}

// ---------- fused prep: blocks [0,1728) do D->Dbf/Dt2 via DMA-flat LDS; [1728,2016) F->Fbf
__global__ void k_prep(const float* __restrict__ F, const float* __restrict__ D,
                       const float* __restrict__ qw,
                       __hip_bfloat16* __restrict__ Fbf,
                       __hip_bfloat16* __restrict__ Dbf, __hip_bfloat16* __restrict__ Dt2) {
    __shared__ __align__(16) float T[9152];   // flat 32*286 fp32 = 36608 B
    __shared__ float qs[24];
    int t = threadIdx.x;
    int bid = blockIdx.x;
    if (bid >= NTILES) {
        // ---- prep_f: F -> bf16 [256][288], scaled by 1/s
        int o = (bid - NTILES) * 256 + t;    // 288*256 == 73728 exactly
        int row = o / DIMP, col = o % DIMP;
        float v = (col < DIM) ? F[row * DIM + col] * INV_S : 0.f;
        Fbf[o] = __float2bfloat16(v);
        return;
    }
    int z0 = bid * 32;
    if (t < 24) qs[t] = qw[t] * S_CONST;
    // DMA: 36608 B = 35 full 1KB chunks + 768 B tail (48 lanes)
    {
        int wave = t >> 6, lane = t & 63;
        const char* src = (const char*)(D + (size_t)z0 * DIM);
        char* dst = (char*)T;
        #pragma unroll
        for (int j = 0; j < 9; ++j) {
            int c = wave + j * 4;
            if (c < 35 || (c == 35 && lane < 48))
                gload_lds16(src + c * 1024 + lane * 16, dst + c * 1024);
        }
    }
    asm volatile("s_waitcnt vmcnt(0)" ::: "memory");
    __syncthreads();
    // Dbf: lane-consecutive float2 -> bf162, 4608 dwords (18 iters), conflict-free b64 reads
    for (int m = 0; m < 18; ++m) {
        int d = t + m * 256;                 // 0..4607
        int z = d / 144, i2 = d % 144;
        int i = i2 * 2;
        __hip_bfloat162 o2;
        if (i < DIM) {
            float2 v = *(const float2*)(&T[z * DIM + i]);   // z*286+i even -> 8B aligned
            o2.x = __float2bfloat16(v.x); o2.y = __float2bfloat16(v.y);
        } else {
            o2.x = __float2bfloat16(0.f); o2.y = o2.x;      // pad cols 286..287
        }
        *(__hip_bfloat162*)(Dbf + (size_t)(z0 + z) * DIMP + i) = o2;
    }
    // Dt2[tz][i][z] transpose: 288 i * 4 zc = 1152 contiguous 16B writes
    for (int s = 0; s < 5; ++s) {
        int idx = t + s * 256;
        if (idx < 1152) {
            int i = idx >> 2, zc = idx & 3;
            __hip_bfloat16 o8[8];
            #pragma unroll
            for (int j = 0; j < 8; ++j) {
                int zl = zc * 8 + j;
                int y = ((z0 + zl) / NA_) % NB_;
                o8[j] = __float2bfloat16(T[zl * DIM + i] * qs[y]);
            }
            *(bf16x8*)(Dt2 + ((size_t)bid * DIMP + i) * ZC + zc * 8) = *(const bf16x8*)o8;
        }
    }
}

// ---------- fused main, M=32 per wave; epilogue packs acc into coalesced b128 stores
// in a permuted layout that k_reduce decodes.
__launch_bounds__(256, 2)
__global__ void k_main(const __hip_bfloat16* __restrict__ Fbf,
                       const __hip_bfloat16* __restrict__ Dbf,
                       const __hip_bfloat16* __restrict__ Dt2,
                       __hip_bfloat16* __restrict__ part) {
    __shared__ __align__(16) __hip_bfloat16 Ds[32][288];    // [z][i]  18432 B
    __shared__ __align__(16) __hip_bfloat16 Dts[288][32];   // [i][z]  18432 B
    __shared__ __align__(16) __hip_bfloat16 Gs[4][32][32];  // 8192 B -> total 45056 B

    int t = threadIdx.x;
    int wave = t >> 6, lane = t & 63, ln = lane & 15, q = lane >> 4;

    // cache F A-frags for this wave's 32 batch rows (2 halves x 9 K-steps)
    bf16x8 fa[2][9];
    int rowbase = blockIdx.y * 128 + wave * 32;
    #pragma unroll
    for (int h = 0; h < 2; ++h) {
        const __hip_bfloat16* fp = Fbf + (size_t)(rowbase + h * 16 + ln) * DIMP + q * 8;
        #pragma unroll
        for (int ks = 0; ks < 9; ++ks) fa[h][ks] = *(const bf16x8*)(fp + ks * 32);
    }

    f32x4 acc[2][18];
    #pragma unroll
    for (int h = 0; h < 2; ++h)
        #pragma unroll
        for (int n = 0; n < 18; ++n) acc[h][n] = (f32x4){0.f, 0.f, 0.f, 0.f};

    #pragma unroll 1
    for (int k = 0; k < TILES_PER_WG; ++k) {
        int tz = blockIdx.x + k * NCHUNK;
        // stage: waves 0,1 -> Ds halves; waves 2,3 -> Dts halves; 9x1KB DMA each
        {
            const char* src; char* dst;
            if (wave < 2) {
                src = (const char*)(Dbf + (size_t)tz * ZC * DIMP) + wave * 9216 + lane * 16;
                dst = ((char*)&Ds[0][0]) + wave * 9216;
            } else {
                src = (const char*)(Dt2 + (size_t)tz * DIMP * ZC) + (wave - 2) * 9216 + lane * 16;
                dst = ((char*)&Dts[0][0]) + (wave - 2) * 9216;
            }
            #pragma unroll
            for (int j = 0; j < 9; ++j)
                gload_lds16(src + j * 1024, dst + j * 1024);
        }
        asm volatile("s_waitcnt vmcnt(0)" ::: "memory");   // DMA landed
        __syncthreads();
        // GEMM1: G[32 x 32] per wave, K=288; B-frags read once for 2 row-halves
        f32x4 g00 = (f32x4){0.f,0.f,0.f,0.f}, g01 = (f32x4){0.f,0.f,0.f,0.f};
        f32x4 g10 = (f32x4){0.f,0.f,0.f,0.f}, g11 = (f32x4){0.f,0.f,0.f,0.f};
        #pragma unroll
        for (int ks = 0; ks < 9; ++ks) {
            bf16x8 b0 = *(const bf16x8*)(&Ds[ln][ks * 32 + q * 8]);
            bf16x8 b1 = *(const bf16x8*)(&Ds[16 + ln][ks * 32 + q * 8]);
            g00 = __builtin_amdgcn_mfma_f32_16x16x32_bf16(fa[0][ks], b0, g00, 0, 0, 0);
            g01 = __builtin_amdgcn_mfma_f32_16x16x32_bf16(fa[0][ks], b1, g01, 0, 0, 0);
            g10 = __builtin_amdgcn_mfma_f32_16x16x32_bf16(fa[1][ks], b0, g10, 0, 0, 0);
            g11 = __builtin_amdgcn_mfma_f32_16x16x32_bf16(fa[1][ks], b1, g11, 0, 0, 0);
        }
        // act + C-layout -> A-layout relayout (per-wave LDS, no barrier)
        #pragma unroll
        for (int h = 0; h < 2; ++h) {
            #pragma unroll
            for (int zh = 0; zh < 2; ++zh) {
                f32x4 g = (h == 0) ? (zh == 0 ? g00 : g01) : (zh == 0 ? g10 : g11);
                #pragma unroll
                for (int r = 0; r < 4; ++r) {
                    float x = g[r];
                    float a = fabsf(x);
                    float e = __expf(-2.f * a);
                    float th = (1.f - e) / (1.f + e);
                    float v = copysignf(ACT_CST * th, x);
                    Gs[wave][h * 16 + q * 4 + r][zh * 16 + ln] = __float2bfloat16(v);
                }
            }
        }
        // GEMM2: Out[32 x 288] += P[32 x 32] * Dts; B-frags read once for 2 row-halves
        bf16x8 a20 = *(const bf16x8*)(&Gs[wave][ln][q * 8]);
        bf16x8 a21 = *(const bf16x8*)(&Gs[wave][16 + ln][q * 8]);
        #pragma unroll
        for (int nf = 0; nf < 18; ++nf) {
            bf16x8 b2 = *(const bf16x8*)(&Dts[nf * 16 + ln][q * 8]);
            acc[0][nf] = __builtin_amdgcn_mfma_f32_16x16x32_bf16(a20, b2, acc[0][nf], 0, 0, 0);
            acc[1][nf] = __builtin_amdgcn_mfma_f32_16x16x32_bf16(a21, b2, acc[1][nf], 0, 0, 0);
        }
        __syncthreads();   // protect Ds/Dts before next stage
    }
    // epilogue: permuted coalesced layout, 18 b128 stores/thread.
    // elem ((h*9+m)*64 + lane)*8 + j  <=>  acc[h][2m + (j>>2)][j&3]
    __hip_bfloat16* pw = part + (size_t)blockIdx.x * (NBATCH * DIMP)
                       + ((size_t)blockIdx.y * 128 + wave * 32) * DIMP;
    #pragma unroll
    for (int h = 0; h < 2; ++h) {
        #pragma unroll
        for (int m = 0; m < 9; ++m) {
            __hip_bfloat16 o8[8];
            #pragma unroll
            for (int j = 0; j < 8; ++j)
                o8[j] = __float2bfloat16(acc[h][2 * m + (j >> 2)][j & 3]);
            *(bf16x8*)(pw + (size_t)((h * 9 + m) * 64 + lane) * 8) = *(const bf16x8*)o8;
        }
    }
}

// ---------- reduce permuted bf16 partials over 192 z-chunks: 576 blocks x 16 slots
__global__ void k_reduce(const __hip_bfloat16* __restrict__ part, float* __restrict__ out) {
    __shared__ float red[3][16][8];
    int t = threadIdx.x, wave = t >> 6, lane = t & 63;
    int j = lane & 15;                 // slot within block
    int zg = wave * 4 + (lane >> 4);   // 0..15 zc-group
    int s = blockIdx.x * 16 + j;       // 576*16 = 9216 b128 slots per chunk
    const __hip_bfloat16* p = part + (size_t)s * 8;
    float sum[8];
    #pragma unroll
    for (int kk = 0; kk < 8; ++kk) sum[kk] = 0.f;
    #pragma unroll 4
    for (int ii = 0; ii < 12; ++ii) {
        bf16x8 v = *(const bf16x8*)(p + (size_t)(zg * 12 + ii) * (NBATCH * DIMP));
        #pragma unroll
        for (int kk = 0; kk < 8; ++kk) {
            __hip_bfloat16 h; *(short*)&h = v[kk];
            sum[kk] += __bfloat162float(h);
        }
    }
    // intra-wave: fold the 4 zc-groups (lane strides 16, 32)
    #pragma unroll
    for (int kk = 0; kk < 8; ++kk) {
        sum[kk] += __shfl_down(sum[kk], 16);
        sum[kk] += __shfl_down(sum[kk], 32);
    }
    if (wave > 0 && lane < 16) {
        #pragma unroll
        for (int kk = 0; kk < 8; ++kk) red[wave - 1][lane][kk] = sum[kk];
    }
    __syncthreads();
    if (wave == 0 && lane < 16) {
        #pragma unroll
        for (int w = 0; w < 3; ++w)
            #pragma unroll
            for (int kk = 0; kk < 8; ++kk) sum[kk] += red[w][lane][kk];
        // decode slot s -> (rows, cols)
        int wr = s / 1152, si = s % 1152;
        int lane_m = si % 64, m9 = si / 64;
        int h = m9 / 9, m = m9 % 9, q = lane_m >> 4, ln = lane_m & 15;
        int rowb = wr * 32 + h * 16 + q * 4;
        #pragma unroll
        for (int j8 = 0; j8 < 8; ++j8) {
            int nf = 2 * m + (j8 >> 2), r = j8 & 3;
            int i = nf * 16 + ln;
            if (i < DIM) out[(rowb + r) * DIM + i] = sum[j8];
        }
    }
}

extern "C" void kernel_launch(void* const* d_in, const int* in_sizes, int n_in,
                              void* d_out, int out_size, void* d_ws, size_t ws_size,
                              hipStream_t stream) {
    const float* F  = (const float*)d_in[0];
    const float* D  = (const float*)d_in[1];
    const float* qw = (const float*)d_in[2];
    char* ws = (char*)d_ws;
    __hip_bfloat16* Fbf = (__hip_bfloat16*)(ws + WS_FBF);
    __hip_bfloat16* Dbf = (__hip_bfloat16*)(ws + WS_DBF);
    __hip_bfloat16* Dt2 = (__hip_bfloat16*)(ws + WS_DT);
    __hip_bfloat16* part = (__hip_bfloat16*)(ws + WS_PART);

    k_prep<<<NTILES + 288, 256, 0, stream>>>(F, D, qw, Fbf, Dbf, Dt2);
    k_main<<<dim3(NCHUNK, 2), 256, 0, stream>>>(Fbf, Dbf, Dt2, part);
    k_reduce<<<576, 256, 0, stream>>>(part, (float*)d_out);
}

// Round 15
// 139.929 us; speedup vs baseline: 1.1024x; 1.0146x over previous
//
#include <hip/hip_runtime.h>
#include <hip/hip_bf16.h>

#define DIM    286
#define DIMP   288
#define NZTOT  55296     // 48*24*48
#define NBATCH 256
#define NB_    24
#define NA_    48
#define ZC     32        // z per tile
#define NTILES 1728      // NZTOT/ZC
#define NCHUNK 192       // z-chunk workgroups (grid.x)
#define TILES_PER_WG 9   // NTILES/NCHUNK
#define S_CONST 16.911534525287763f
#define INV_S   0.05913123959890826f
#define ACT_CST 1.5927f  // normalize2mom const for tanh
#define TWO_LOG2E 2.8853900817779268f   // 2*log2(e): expf(-2a) == exp2(-TWO_LOG2E*a)

typedef short bf16x8 __attribute__((ext_vector_type(8)));
typedef float f32x4  __attribute__((ext_vector_type(4)));

// ws layout (bytes)
#define WS_FBF  0u
#define WS_DBF  147456u                      // Fbf: 256*288*2
#define WS_DT   (WS_DBF + 31850496u)         // Dbf: 55296*288*2
#define WS_PART (WS_DT + 31850496u)          // Dt2: 1728 tiles * 288 * 32 * 2
                                             // part (bf16): 192*256*288*2 = 28311552

typedef const __attribute__((address_space(1))) char GA;
typedef __attribute__((address_space(3))) char LA;
__device__ __forceinline__ void gload_lds16(const void* g, void* l) {
    __builtin_amdgcn_global_load_lds((GA*)g, (LA*)l, 16, 0, 0);
}

// ---------- fused prep: blocks [0,1728) do D->Dbf/Dt2 via DMA-flat LDS; [1728,2016) F->Fbf
__global__ void k_prep(const float* __restrict__ F, const float* __restrict__ D,
                       const float* __restrict__ qw,
                       __hip_bfloat16* __restrict__ Fbf,
                       __hip_bfloat16* __restrict__ Dbf, __hip_bfloat16* __restrict__ Dt2) {
    __shared__ __align__(16) float T[9152];   // flat 32*286 fp32 = 36608 B
    __shared__ float qs[24];
    int t = threadIdx.x;
    int bid = blockIdx.x;
    if (bid >= NTILES) {
        // ---- prep_f: F -> bf16 [256][288], scaled by 1/s
        int o = (bid - NTILES) * 256 + t;    // 288*256 == 73728 exactly
        int row = o / DIMP, col = o % DIMP;
        float v = (col < DIM) ? F[row * DIM + col] * INV_S : 0.f;
        Fbf[o] = __float2bfloat16(v);
        return;
    }
    int z0 = bid * 32;
    if (t < 24) qs[t] = qw[t] * S_CONST;
    // DMA: 36608 B = 35 full 1KB chunks + 768 B tail (48 lanes)
    {
        int wave = t >> 6, lane = t & 63;
        const char* src = (const char*)(D + (size_t)z0 * DIM);
        char* dst = (char*)T;
        #pragma unroll
        for (int j = 0; j < 9; ++j) {
            int c = wave + j * 4;
            if (c < 35 || (c == 35 && lane < 48))
                gload_lds16(src + c * 1024 + lane * 16, dst + c * 1024);
        }
    }
    asm volatile("s_waitcnt vmcnt(0)" ::: "memory");
    __syncthreads();
    // Dbf: lane-consecutive float2 -> bf162, 4608 dwords (18 iters), conflict-free b64 reads
    for (int m = 0; m < 18; ++m) {
        int d = t + m * 256;                 // 0..4607
        int z = d / 144, i2 = d % 144;
        int i = i2 * 2;
        __hip_bfloat162 o2;
        if (i < DIM) {
            float2 v = *(const float2*)(&T[z * DIM + i]);   // z*286+i even -> 8B aligned
            o2.x = __float2bfloat16(v.x); o2.y = __float2bfloat16(v.y);
        } else {
            o2.x = __float2bfloat16(0.f); o2.y = o2.x;      // pad cols 286..287
        }
        *(__hip_bfloat162*)(Dbf + (size_t)(z0 + z) * DIMP + i) = o2;
    }
    // Dt2[tz][i][z] transpose: 288 i * 4 zc = 1152 contiguous 16B writes
    for (int s = 0; s < 5; ++s) {
        int idx = t + s * 256;
        if (idx < 1152) {
            int i = idx >> 2, zc = idx & 3;
            __hip_bfloat16 o8[8];
            #pragma unroll
            for (int j = 0; j < 8; ++j) {
                int zl = zc * 8 + j;
                int y = ((z0 + zl) / NA_) % NB_;
                o8[j] = __float2bfloat16(T[zl * DIM + i] * qs[y]);
            }
            *(bf16x8*)(Dt2 + ((size_t)bid * DIMP + i) * ZC + zc * 8) = *(const bf16x8*)o8;
        }
    }
}

// ---------- fused main, M=32 per wave (R10 structure) + contiguous tile mapping
// + rcp-based tanh. Epilogue packs acc into coalesced b128 stores (permuted).
__launch_bounds__(256, 2)
__global__ void k_main(const __hip_bfloat16* __restrict__ Fbf,
                       const __hip_bfloat16* __restrict__ Dbf,
                       const __hip_bfloat16* __restrict__ Dt2,
                       __hip_bfloat16* __restrict__ part) {
    __shared__ __align__(16) __hip_bfloat16 Ds[32][288];    // [z][i]  18432 B
    __shared__ __align__(16) __hip_bfloat16 Dts[288][32];   // [i][z]  18432 B
    __shared__ __align__(16) __hip_bfloat16 Gs[4][32][32];  // 8192 B -> total 45056 B

    int t = threadIdx.x;
    int wave = t >> 6, lane = t & 63, ln = lane & 15, q = lane >> 4;

    // cache F A-frags for this wave's 32 batch rows (2 halves x 9 K-steps)
    bf16x8 fa[2][9];
    int rowbase = blockIdx.y * 128 + wave * 32;
    #pragma unroll
    for (int h = 0; h < 2; ++h) {
        const __hip_bfloat16* fp = Fbf + (size_t)(rowbase + h * 16 + ln) * DIMP + q * 8;
        #pragma unroll
        for (int ks = 0; ks < 9; ++ks) fa[h][ks] = *(const bf16x8*)(fp + ks * 32);
    }

    f32x4 acc[2][18];
    #pragma unroll
    for (int h = 0; h < 2; ++h)
        #pragma unroll
        for (int n = 0; n < 18; ++n) acc[h][n] = (f32x4){0.f, 0.f, 0.f, 0.f};

    #pragma unroll 1
    for (int k = 0; k < TILES_PER_WG; ++k) {
        int tz = blockIdx.x * TILES_PER_WG + k;   // contiguous 332KB span per block
        // stage: waves 0,1 -> Ds halves; waves 2,3 -> Dts halves; 9x1KB DMA each
        {
            const char* src; char* dst;
            if (wave < 2) {
                src = (const char*)(Dbf + (size_t)tz * ZC * DIMP) + wave * 9216 + lane * 16;
                dst = ((char*)&Ds[0][0]) + wave * 9216;
            } else {
                src = (const char*)(Dt2 + (size_t)tz * DIMP * ZC) + (wave - 2) * 9216 + lane * 16;
                dst = ((char*)&Dts[0][0]) + (wave - 2) * 9216;
            }
            #pragma unroll
            for (int j = 0; j < 9; ++j)
                gload_lds16(src + j * 1024, dst + j * 1024);
        }
        asm volatile("s_waitcnt vmcnt(0)" ::: "memory");   // DMA landed
        __syncthreads();
        // GEMM1: G[32 x 32] per wave, K=288; B-frags read once for 2 row-halves
        f32x4 g00 = (f32x4){0.f,0.f,0.f,0.f}, g01 = (f32x4){0.f,0.f,0.f,0.f};
        f32x4 g10 = (f32x4){0.f,0.f,0.f,0.f}, g11 = (f32x4){0.f,0.f,0.f,0.f};
        #pragma unroll
        for (int ks = 0; ks < 9; ++ks) {
            bf16x8 b0 = *(const bf16x8*)(&Ds[ln][ks * 32 + q * 8]);
            bf16x8 b1 = *(const bf16x8*)(&Ds[16 + ln][ks * 32 + q * 8]);
            g00 = __builtin_amdgcn_mfma_f32_16x16x32_bf16(fa[0][ks], b0, g00, 0, 0, 0);
            g01 = __builtin_amdgcn_mfma_f32_16x16x32_bf16(fa[0][ks], b1, g01, 0, 0, 0);
            g10 = __builtin_amdgcn_mfma_f32_16x16x32_bf16(fa[1][ks], b0, g10, 0, 0, 0);
            g11 = __builtin_amdgcn_mfma_f32_16x16x32_bf16(fa[1][ks], b1, g11, 0, 0, 0);
        }
        // act = ACT_CST*tanh(g) via v_exp + v_rcp: tanh(a) = 1 - 2e/(1+e), e = 2^(-2*log2e*a)
        #pragma unroll
        for (int h = 0; h < 2; ++h) {
            #pragma unroll
            for (int zh = 0; zh < 2; ++zh) {
                f32x4 g = (h == 0) ? (zh == 0 ? g00 : g01) : (zh == 0 ? g10 : g11);
                #pragma unroll
                for (int r = 0; r < 4; ++r) {
                    float x = g[r];
                    float a = fabsf(x);
                    float e = __builtin_amdgcn_exp2f(-TWO_LOG2E * a);
                    float v = ACT_CST - 2.f * ACT_CST * e * __builtin_amdgcn_rcpf(1.f + e);
                    v = copysignf(v, x);
                    Gs[wave][h * 16 + q * 4 + r][zh * 16 + ln] = __float2bfloat16(v);
                }
            }
        }
        // GEMM2: Out[32 x 288] += P[32 x 32] * Dts; B-frags read once for 2 row-halves
        bf16x8 a20 = *(const bf16x8*)(&Gs[wave][ln][q * 8]);
        bf16x8 a21 = *(const bf16x8*)(&Gs[wave][16 + ln][q * 8]);
        #pragma unroll
        for (int nf = 0; nf < 18; ++nf) {
            bf16x8 b2 = *(const bf16x8*)(&Dts[nf * 16 + ln][q * 8]);
            acc[0][nf] = __builtin_amdgcn_mfma_f32_16x16x32_bf16(a20, b2, acc[0][nf], 0, 0, 0);
            acc[1][nf] = __builtin_amdgcn_mfma_f32_16x16x32_bf16(a21, b2, acc[1][nf], 0, 0, 0);
        }
        __syncthreads();   // protect Ds/Dts before next stage
    }
    // epilogue: permuted coalesced layout, 18 b128 stores/thread.
    // elem ((h*9+m)*64 + lane)*8 + j  <=>  acc[h][2m + (j>>2)][j&3]
    __hip_bfloat16* pw = part + (size_t)blockIdx.x * (NBATCH * DIMP)
                       + ((size_t)blockIdx.y * 128 + wave * 32) * DIMP;
    #pragma unroll
    for (int h = 0; h < 2; ++h) {
        #pragma unroll
        for (int m = 0; m < 9; ++m) {
            __hip_bfloat16 o8[8];
            #pragma unroll
            for (int j = 0; j < 8; ++j)
                o8[j] = __float2bfloat16(acc[h][2 * m + (j >> 2)][j & 3]);
            *(bf16x8*)(pw + (size_t)((h * 9 + m) * 64 + lane) * 8) = *(const bf16x8*)o8;
        }
    }
}

// ---------- reduce permuted bf16 partials over 192 z-chunks: 576 blocks x 16 slots
__global__ void k_reduce(const __hip_bfloat16* __restrict__ part, float* __restrict__ out) {
    __shared__ float red[3][16][8];
    int t = threadIdx.x, wave = t >> 6, lane = t & 63;
    int j = lane & 15;                 // slot within block
    int zg = wave * 4 + (lane >> 4);   // 0..15 zc-group
    int s = blockIdx.x * 16 + j;       // 576*16 = 9216 b128 slots per chunk
    const __hip_bfloat16* p = part + (size_t)s * 8;
    float sum[8];
    #pragma unroll
    for (int kk = 0; kk < 8; ++kk) sum[kk] = 0.f;
    #pragma unroll 4
    for (int ii = 0; ii < 12; ++ii) {
        bf16x8 v = *(const bf16x8*)(p + (size_t)(zg * 12 + ii) * (NBATCH * DIMP));
        #pragma unroll
        for (int kk = 0; kk < 8; ++kk) {
            __hip_bfloat16 h; *(short*)&h = v[kk];
            sum[kk] += __bfloat162float(h);
        }
    }
    // intra-wave: fold the 4 zc-groups (lane strides 16, 32)
    #pragma unroll
    for (int kk = 0; kk < 8; ++kk) {
        sum[kk] += __shfl_down(sum[kk], 16);
        sum[kk] += __shfl_down(sum[kk], 32);
    }
    if (wave > 0 && lane < 16) {
        #pragma unroll
        for (int kk = 0; kk < 8; ++kk) red[wave - 1][lane][kk] = sum[kk];
    }
    __syncthreads();
    if (wave == 0 && lane < 16) {
        #pragma unroll
        for (int w = 0; w < 3; ++w)
            #pragma unroll
            for (int kk = 0; kk < 8; ++kk) sum[kk] += red[w][lane][kk];
        // decode slot s -> (rows, cols)
        int wr = s / 1152, si = s % 1152;
        int lane_m = si % 64, m9 = si / 64;
        int h = m9 / 9, m = m9 % 9, q = lane_m >> 4, ln = lane_m & 15;
        int rowb = wr * 32 + h * 16 + q * 4;
        #pragma unroll
        for (int j8 = 0; j8 < 8; ++j8) {
            int nf = 2 * m + (j8 >> 2), r = j8 & 3;
            int i = nf * 16 + ln;
            if (i < DIM) out[(rowb + r) * DIM + i] = sum[j8];
        }
    }
}

extern "C" void kernel_launch(void* const* d_in, const int* in_sizes, int n_in,
                              void* d_out, int out_size, void* d_ws, size_t ws_size,
                              hipStream_t stream) {
    const float* F  = (const float*)d_in[0];
    const float* D  = (const float*)d_in[1];
    const float* qw = (const float*)d_in[2];
    char* ws = (char*)d_ws;
    __hip_bfloat16* Fbf = (__hip_bfloat16*)(ws + WS_FBF);
    __hip_bfloat16* Dbf = (__hip_bfloat16*)(ws + WS_DBF);
    __hip_bfloat16* Dt2 = (__hip_bfloat16*)(ws + WS_DT);
    __hip_bfloat16* part = (__hip_bfloat16*)(ws + WS_PART);

    k_prep<<<NTILES + 288, 256, 0, stream>>>(F, D, qw, Fbf, Dbf, Dt2);
    k_main<<<dim3(NCHUNK, 2), 256, 0, stream>>>(Fbf, Dbf, Dt2, part);
    k_reduce<<<576, 256, 0, stream>>>(part, (float*)d_out);
}